// Round 3
// baseline (269.990 us; speedup 1.0000x reference)
//
#include <hip/hip_runtime.h>
#include <math.h>

// BundleAdjustmentModel: project N 3D points into V=64 camera views.
// out[v][n] = (u,v): u = -f*X/safe_z + cx, v = f*Y/safe_z + cy,
// [X,Y,Z] = R_v * p_n + t_v, R_v = Rx*Ry*Rz (euler xyz),
// t_v = (tx, ty, -(softplus(d)+0.25)), f = softplus(focal_raw)+50.
//
// Memory-bound: 256 MB written, 6 MB read -> ~40 us floor at 6.3 TB/s.
// Each thread owns 2 CONSECUTIVE points (registers), loops all 64 views,
// emits ONE 16-byte nontemporal store per view (1 KB/wave-instr).
// View constants ([R|t] rows as 3 float4) in LDS, broadcast reads.

#define NVIEW 64
#define BLOCK 256
#define Z_EPS 1e-4f

typedef float f32x4 __attribute__((ext_vector_type(4)));  // clang vector: OK for nontemporal builtin

__device__ __forceinline__ float softplus_f(float x) {
    return fmaxf(x, 0.0f) + log1pf(expf(-fabsf(x)));
}

__device__ __forceinline__ void view_setup(
    const float* __restrict__ euler,
    const float* __restrict__ txy,
    const float* __restrict__ tdr,
    float4* vd, int tid)
{
    if (tid < NVIEW) {
        float sx, cx_, sy, cy_, sz, cz;
        sincosf(euler[tid * 3 + 0], &sx, &cx_);
        sincosf(euler[tid * 3 + 1], &sy, &cy_);
        sincosf(euler[tid * 3 + 2], &sz, &cz);
        float r00 = cy_ * cz,                 r01 = -cy_ * sz,                r02 = sy;
        float r10 = cx_ * sz + sx * sy * cz,  r11 = cx_ * cz - sx * sy * sz,  r12 = -sx * cy_;
        float r20 = sx * sz - cx_ * sy * cz,  r21 = sx * cz + cx_ * sy * sz,  r22 = cx_ * cy_;
        float tz = -(softplus_f(tdr[tid]) + 0.25f);
        vd[tid * 3 + 0] = make_float4(r00, r01, r02, txy[tid * 2 + 0]);
        vd[tid * 3 + 1] = make_float4(r10, r11, r12, txy[tid * 2 + 1]);
        vd[tid * 3 + 2] = make_float4(r20, r21, r22, tz);
    }
}

// Fast path: N even. Each thread: points (n0, n0+1), one 16B store/view.
__global__ __launch_bounds__(BLOCK) void ba_project_pair(
    const float* __restrict__ points, const float* __restrict__ euler,
    const float* __restrict__ txy, const float* __restrict__ tdr,
    const float* __restrict__ focal_raw, const int* __restrict__ cxp,
    const int* __restrict__ cyp, f32x4* __restrict__ out4, int N)
{
    __shared__ float4 vd[NVIEW * 3];
    const int tid = threadIdx.x;
    view_setup(euler, txy, tdr, vd, tid);
    __syncthreads();

    const int g  = blockIdx.x * BLOCK + tid;   // pair index
    const int n0 = g * 2;
    if (n0 >= N) return;

    const float focal = softplus_f(focal_raw[0]) + 50.0f;
    const float ccx = (float)cxp[0];
    const float ccy = (float)cyp[0];

    // 6 floats, 8-byte aligned (pair starts at byte 24*g)
    const float2* p2 = (const float2*)(points + (size_t)n0 * 3);
    float2 a = p2[0], b = p2[1], c = p2[2];
    const float px0 = a.x, py0 = a.y, pz0 = b.x;
    const float px1 = b.y, py1 = c.x, pz1 = c.y;

    const int rowStride = N >> 1;              // f32x4s per view row
    f32x4* op = out4 + g;                      // (v*N + n0)/2 with v=0
    const bool full = (n0 + 2 <= N);

#pragma unroll 2
    for (int v = 0; v < NVIEW; ++v) {
        float4 ra = vd[v * 3 + 0];
        float4 rb = vd[v * 3 + 1];
        float4 rc = vd[v * 3 + 2];

        float X0 = fmaf(ra.x, px0, fmaf(ra.y, py0, fmaf(ra.z, pz0, ra.w)));
        float Y0 = fmaf(rb.x, px0, fmaf(rb.y, py0, fmaf(rb.z, pz0, rb.w)));
        float Z0 = fmaf(rc.x, px0, fmaf(rc.y, py0, fmaf(rc.z, pz0, rc.w)));
        float X1 = fmaf(ra.x, px1, fmaf(ra.y, py1, fmaf(ra.z, pz1, ra.w)));
        float Y1 = fmaf(rb.x, px1, fmaf(rb.y, py1, fmaf(rb.z, pz1, rb.w)));
        float Z1 = fmaf(rc.x, px1, fmaf(rc.y, py1, fmaf(rc.z, pz1, rc.w)));

        float s0 = (Z0 >= 0.0f) ? 1.0f : -1.0f;
        float s1 = (Z1 >= 0.0f) ? 1.0f : -1.0f;
        float t0 = focal * __builtin_amdgcn_rcpf(s0 * fmaxf(fabsf(Z0), Z_EPS));
        float t1 = focal * __builtin_amdgcn_rcpf(s1 * fmaxf(fabsf(Z1), Z_EPS));

        f32x4 r;
        r.x = fmaf(-X0, t0, ccx);
        r.y = fmaf( Y0, t0, ccy);
        r.z = fmaf(-X1, t1, ccx);
        r.w = fmaf( Y1, t1, ccy);

        if (full) {
            __builtin_nontemporal_store(r, op);
        } else {  // odd tail point (N odd only)
            float2* o2 = (float2*)op;
            o2[0] = make_float2(r.x, r.y);
        }
        op += rowStride;
    }
}

// Generic fallback (odd N rows would misalign 16B stores).
__global__ __launch_bounds__(BLOCK) void ba_project_scalar(
    const float* __restrict__ points, const float* __restrict__ euler,
    const float* __restrict__ txy, const float* __restrict__ tdr,
    const float* __restrict__ focal_raw, const int* __restrict__ cxp,
    const int* __restrict__ cyp, float2* __restrict__ out, int N)
{
    __shared__ float4 vd[NVIEW * 3];
    const int tid = threadIdx.x;
    view_setup(euler, txy, tdr, vd, tid);
    __syncthreads();

    const int n = blockIdx.x * BLOCK + tid;
    if (n >= N) return;

    const float focal = softplus_f(focal_raw[0]) + 50.0f;
    const float ccx = (float)cxp[0];
    const float ccy = (float)cyp[0];
    const float px = points[n * 3 + 0], py = points[n * 3 + 1], pz = points[n * 3 + 2];

    for (int v = 0; v < NVIEW; ++v) {
        float4 ra = vd[v * 3 + 0], rb = vd[v * 3 + 1], rc = vd[v * 3 + 2];
        float X = fmaf(ra.x, px, fmaf(ra.y, py, fmaf(ra.z, pz, ra.w)));
        float Y = fmaf(rb.x, px, fmaf(rb.y, py, fmaf(rb.z, pz, rb.w)));
        float Z = fmaf(rc.x, px, fmaf(rc.y, py, fmaf(rc.z, pz, rc.w)));
        float s = (Z >= 0.0f) ? 1.0f : -1.0f;
        float t = focal * __builtin_amdgcn_rcpf(s * fmaxf(fabsf(Z), Z_EPS));
        out[(size_t)v * N + n] = make_float2(fmaf(-X, t, ccx), fmaf(Y, t, ccy));
    }
}

extern "C" void kernel_launch(void* const* d_in, const int* in_sizes, int n_in,
                              void* d_out, int out_size, void* d_ws, size_t ws_size,
                              hipStream_t stream) {
    const float* points    = (const float*)d_in[0];
    const float* euler     = (const float*)d_in[1];
    const float* txy       = (const float*)d_in[2];
    const float* tdr       = (const float*)d_in[3];
    const float* focal_raw = (const float*)d_in[4];
    const int*   cxp       = (const int*)d_in[5];
    const int*   cyp       = (const int*)d_in[6];

    const int N = in_sizes[0] / 3;

    if ((N & 1) == 0) {
        const int pairs  = N / 2;
        const int blocks = (pairs + BLOCK - 1) / BLOCK;
        ba_project_pair<<<blocks, BLOCK, 0, stream>>>(
            points, euler, txy, tdr, focal_raw, cxp, cyp, (f32x4*)d_out, N);
    } else {
        const int blocks = (N + BLOCK - 1) / BLOCK;
        ba_project_scalar<<<blocks, BLOCK, 0, stream>>>(
            points, euler, txy, tdr, focal_raw, cxp, cyp, (float2*)d_out, N);
    }
}